// Round 3
// baseline (1716.327 us; speedup 1.0000x reference)
//
#include <hip/hip_runtime.h>

#define N_TOK 32768
#define D_ 512
#define F_ 2048
#define E_ 8
#define M_TILE 128
#define BF_ 128
#define NSLOT_MAX 66560   // 65536 + 8*128 padding, 128-aligned per expert

typedef __attribute__((ext_vector_type(8))) short bf16x8;
typedef __attribute__((ext_vector_type(8))) unsigned short us8;
typedef __attribute__((ext_vector_type(4))) float f32x4;

__device__ __forceinline__ unsigned short f2bf(float f) {
  union { float f; unsigned u; } v; v.f = f;
  unsigned r = v.u + 0x7fffu + ((v.u >> 16) & 1u);   // RNE; inputs finite
  return (unsigned short)(r >> 16);
}

// src [E][R][C] f32  ->  dst [E][C][R] bf16 (used for W1 -> [E][F][D])
__global__ void transpose_cvt_k(const float* __restrict__ src,
                                unsigned short* __restrict__ dst, int R, int C) {
  __shared__ unsigned short tl[32][33];
  const int e = blockIdx.z;
  const size_t base = (size_t)e * R * C;
  const int c0 = blockIdx.x * 32, r0 = blockIdx.y * 32;
  const int tx = threadIdx.x, ty = threadIdx.y;
#pragma unroll
  for (int i = 0; i < 4; ++i) {
    int r = ty + i * 8;
    tl[r][tx] = f2bf(src[base + (size_t)(r0 + r) * C + c0 + tx]);
  }
  __syncthreads();
#pragma unroll
  for (int i = 0; i < 4; ++i) {
    int r = ty + i * 8;
    dst[base + (size_t)(c0 + r) * R + r0 + tx] = tl[tx][r];
  }
}

// W2 [E][F][D] f32 -> fragment-ordered bf16:
// dest[((e*64+fb)*32+db)*512 + lane*8 + j] = bf16(W2[e][fb*32+(lane>>4)*8+j][db*16+(lane&15)])
__global__ void cvtW2_k(const float* __restrict__ W2, unsigned short* __restrict__ W2B) {
  const int gid = blockIdx.x * 256 + threadIdx.x;    // 1,048,576 total
  const int l  = gid & 63;
  const int db = (gid >> 6) & 31;
  const int fb = (gid >> 11) & 63;
  const int e  = gid >> 17;
  const int d  = db * 16 + (l & 15);
  const int f0 = fb * 32 + (l >> 4) * 8;
  const float* src = W2 + ((size_t)e * F_ + f0) * D_ + d;
  us8 v;
#pragma unroll
  for (int j = 0; j < 8; ++j) v[j] = f2bf(src[(size_t)j * D_]);
  *reinterpret_cast<us8*>(W2B + (size_t)gid * 8) = v;
}

// one wave per token: logits = x_row @ Wr, softmax fp32, top-2. NO atomics.
__global__ void router_k(const float* __restrict__ x, const float* __restrict__ Wr,
                         int* __restrict__ ridx, float* __restrict__ rw) {
  const int wid = threadIdx.x >> 6, lane = threadIdx.x & 63;
  const int t = blockIdx.x * 4 + wid;
  const float* xr = x + (size_t)t * D_ + lane * 8;
  const float4 xa = *reinterpret_cast<const float4*>(xr);
  const float4 xb = *reinterpret_cast<const float4*>(xr + 4);
  float xv[8] = {xa.x, xa.y, xa.z, xa.w, xb.x, xb.y, xb.z, xb.w};
  float lg[8] = {0, 0, 0, 0, 0, 0, 0, 0};
#pragma unroll
  for (int j = 0; j < 8; ++j) {
    const float* wr = Wr + (size_t)(lane * 8 + j) * E_;
    float4 w0 = *reinterpret_cast<const float4*>(wr);
    float4 w1 = *reinterpret_cast<const float4*>(wr + 4);
    lg[0] += xv[j] * w0.x; lg[1] += xv[j] * w0.y; lg[2] += xv[j] * w0.z; lg[3] += xv[j] * w0.w;
    lg[4] += xv[j] * w1.x; lg[5] += xv[j] * w1.y; lg[6] += xv[j] * w1.z; lg[7] += xv[j] * w1.w;
  }
#pragma unroll
  for (int off = 32; off; off >>= 1) {
#pragma unroll
    for (int q = 0; q < 8; ++q) lg[q] += __shfl_xor(lg[q], off);
  }
  if (lane == 0) {
    float m = lg[0];
#pragma unroll
    for (int q = 1; q < 8; ++q) m = fmaxf(m, lg[q]);
    float p[8]; float s = 0.f;
#pragma unroll
    for (int q = 0; q < 8; ++q) { p[q] = expf(lg[q] - m); s += p[q]; }
    float inv = 1.f / s;
    int e1 = 0;
#pragma unroll
    for (int q = 1; q < 8; ++q) if (p[q] > p[e1]) e1 = q;
    int e2 = (e1 == 0) ? 1 : 0;
#pragma unroll
    for (int q = 0; q < 8; ++q) { if (q == e1) continue; if (p[q] > p[e2]) e2 = q; }
    ridx[2 * t] = e1; ridx[2 * t + 1] = e2;
    rw[2 * t] = p[e1] * inv; rw[2 * t + 1] = p[e2] * inv;
  }
}

// single block: counts, 128-padded offsets, zero cursors
__global__ void count_k(const int* __restrict__ ridx, int* __restrict__ ctrl) {
  __shared__ int h[E_];
  const int tid = threadIdx.x;   // 1024
  if (tid < E_) h[tid] = 0;
  __syncthreads();
  int c0=0,c1=0,c2=0,c3=0,c4=0,c5=0,c6=0,c7=0;
  for (int i = tid; i < 2 * N_TOK; i += 1024) {
    int v = ridx[i];
    c0 += (v == 0); c1 += (v == 1); c2 += (v == 2); c3 += (v == 3);
    c4 += (v == 4); c5 += (v == 5); c6 += (v == 6); c7 += (v == 7);
  }
  atomicAdd(&h[0], c0); atomicAdd(&h[1], c1); atomicAdd(&h[2], c2); atomicAdd(&h[3], c3);
  atomicAdd(&h[4], c4); atomicAdd(&h[5], c5); atomicAdd(&h[6], c6); atomicAdd(&h[7], c7);
  __syncthreads();
  if (tid == 0) {
    int a = 0;
    for (int e = 0; e < E_; ++e) {
      ctrl[e] = h[e];
      ctrl[8 + e] = a;
      a += (h[e] + 127) & ~127;
      ctrl[16 + e] = 0;
    }
    ctrl[24] = a;
  }
}

// per-block LDS ranks + 8 global atomics per block
__global__ void scatter_k(const int* __restrict__ ridx, const float* __restrict__ rw,
                          int* __restrict__ ctrl, int* __restrict__ ptok,
                          float* __restrict__ pgate) {
  __shared__ int h[E_], base[E_];
  const int tid = threadIdx.x;                 // 512
  const int g = blockIdx.x * 512 + tid;        // entry id
  if (tid < E_) h[tid] = 0;
  __syncthreads();
  const int e = ridx[g];
  const int r = atomicAdd(&h[e], 1);           // LDS atomic
  __syncthreads();
  if (tid < E_) base[tid] = atomicAdd(&ctrl[16 + tid], h[tid]);
  __syncthreads();
  const int pos = ctrl[8 + e] + base[e] + r;
  ptok[pos] = g >> 1;
  pgate[pos] = rw[g];
}

// permuted bf16 activations; pad slots zero-filled. one wave per slot.
__global__ void gather_k(const float* __restrict__ x, const int* __restrict__ ptok,
                         const int* __restrict__ ctrl, unsigned short* __restrict__ Xp) {
  const int wid = threadIdx.x >> 6, lane = threadIdx.x & 63;
  const int slot = blockIdx.x * 4 + wid;
  bool valid = false;
#pragma unroll
  for (int e = 0; e < E_; ++e) {
    int off = ctrl[8 + e], c = ctrl[e];
    valid = valid || (slot >= off && slot < off + c);
  }
  us8 v;
  if (valid) {
    const int tok = ptok[slot];
    const float* src = x + (size_t)tok * D_ + lane * 8;
    float4 a = *reinterpret_cast<const float4*>(src);
    float4 b = *reinterpret_cast<const float4*>(src + 4);
    v[0] = f2bf(a.x); v[1] = f2bf(a.y); v[2] = f2bf(a.z); v[3] = f2bf(a.w);
    v[4] = f2bf(b.x); v[5] = f2bf(b.y); v[6] = f2bf(b.z); v[7] = f2bf(b.w);
  } else {
    v = (us8){0, 0, 0, 0, 0, 0, 0, 0};
  }
  *reinterpret_cast<us8*>(Xp + (size_t)slot * D_ + lane * 8) = v;
}

// GEMM1 fragments direct from global (L2-hot), H handoff via LDS, GEMM2 frag-ordered
// global W2. Only 2 barriers per jF iteration. Expert<->XCD affinity: e = gid & 7.
__global__ __launch_bounds__(512, 2) void ffn_k(
    const unsigned short* __restrict__ Xp,
    const unsigned short* __restrict__ W1T,   // [E][F][D] bf16 row-major
    const unsigned short* __restrict__ W2B,   // fragment-ordered
    const int* __restrict__ ptok, const float* __restrict__ pgate,
    const int* __restrict__ ctrl, float* __restrict__ out) {
  const int gid = blockIdx.x;
  const int e = gid & 7;                      // XCD affinity: consecutive gid round-robin XCDs
  const int cnt = ctrl[e];
  const int tile0 = (gid >> 3) * M_TILE;
  if (tile0 >= cnt) return;
  const int slot0 = ctrl[8 + e] + tile0;

  __shared__ unsigned short Hs[M_TILE][BF_ + 8];
  __shared__ int   toks[M_TILE];
  __shared__ float gts[M_TILE];

  const int tid = threadIdx.x;
  if (tid < M_TILE) {
    int slot = tile0 + tid;
    toks[tid] = (slot < cnt) ? ptok[slot0 + tid] : 0;
    gts[tid]  = (slot < cnt) ? pgate[slot0 + tid] : 0.f;
  }

  const int wid = tid >> 6, lane = tid & 63;
  const int lr = lane & 15, lg4 = lane >> 4;
  const int wm1 = wid >> 1, wn1 = wid & 1;   // GEMM1: 4x2 waves over 128x128
  const int wm2 = wid >> 2, wn2 = wid & 3;   // GEMM2: 2x4 waves over 128x512

  const unsigned short* XB  = Xp + (size_t)slot0 * D_;
  const unsigned short* W1e = W1T + (size_t)e * (F_ * D_);
  const unsigned short* W2e = W2B + (size_t)e * (F_ * D_);

  // per-lane GEMM1 fragment base pointers (advance by kb*32 along k)
  const unsigned short* xf0 = XB + (size_t)(wm1 * 32 + lr) * D_ + lg4 * 8;

  f32x4 acc[4][8];
#pragma unroll
  for (int i = 0; i < 4; ++i)
#pragma unroll
    for (int j = 0; j < 8; ++j) acc[i][j] = {0.f, 0.f, 0.f, 0.f};

  for (int jF = 0; jF < F_; jF += BF_) {
    f32x4 hacc[2][4];
#pragma unroll
    for (int i = 0; i < 2; ++i)
#pragma unroll
      for (int j = 0; j < 4; ++j) hacc[i][j] = {0.f, 0.f, 0.f, 0.f};

    const unsigned short* wf0 = W1e + (size_t)(jF + wn1 * 64 + lr) * D_ + lg4 * 8;

#pragma unroll
    for (int kb = 0; kb < 16; ++kb) {         // K = 512, 32 per step
      bf16x8 af[2], bw[4];
#pragma unroll
      for (int mi = 0; mi < 2; ++mi)
        af[mi] = *reinterpret_cast<const bf16x8*>(xf0 + (size_t)mi * 16 * D_ + kb * 32);
#pragma unroll
      for (int ni = 0; ni < 4; ++ni)
        bw[ni] = *reinterpret_cast<const bf16x8*>(wf0 + (size_t)ni * 16 * D_ + kb * 32);
#pragma unroll
      for (int mi = 0; mi < 2; ++mi)
#pragma unroll
        for (int ni = 0; ni < 4; ++ni)
          hacc[mi][ni] = __builtin_amdgcn_mfma_f32_16x16x32_bf16(af[mi], bw[ni], hacc[mi][ni], 0, 0, 0);
    }

    // exact GELU -> Hs (bf16)
#pragma unroll
    for (int mi = 0; mi < 2; ++mi)
#pragma unroll
      for (int ni = 0; ni < 4; ++ni)
#pragma unroll
        for (int r = 0; r < 4; ++r) {
          float v = hacc[mi][ni][r];
          float g = 0.5f * v * (1.f + erff(v * 0.70710678118654752f));
          Hs[wm1 * 32 + mi * 16 + lg4 * 4 + r][wn1 * 64 + ni * 16 + lr] = f2bf(g);
        }
    __syncthreads();

    // GEMM2: A from Hs (padded LDS, ~conflict-free), B from W2B (global, coalesced)
#pragma unroll
    for (int kb2 = 0; kb2 < 4; ++kb2) {
      const int fb = (jF >> 5) + kb2;
      bf16x8 bw2[8], ah[4];
#pragma unroll
      for (int ni = 0; ni < 8; ++ni)
        bw2[ni] = *reinterpret_cast<const bf16x8*>(W2e + ((size_t)fb * 32 + wn2 * 8 + ni) * 512 + lane * 8);
#pragma unroll
      for (int mi = 0; mi < 4; ++mi)
        ah[mi] = *reinterpret_cast<const bf16x8*>(&Hs[wm2 * 64 + mi * 16 + lr][kb2 * 32 + lg4 * 8]);
#pragma unroll
      for (int mi = 0; mi < 4; ++mi)
#pragma unroll
        for (int ni = 0; ni < 8; ++ni)
          acc[mi][ni] = __builtin_amdgcn_mfma_f32_16x16x32_bf16(ah[mi], bw2[ni], acc[mi][ni], 0, 0, 0);
    }
    __syncthreads();
  }

  // epilogue: scale by gate, atomic-add (exactly 2 adds/elem -> deterministic)
  const int rowLim = cnt - tile0;
#pragma unroll
  for (int mi = 0; mi < 4; ++mi) {
#pragma unroll
    for (int r = 0; r < 4; ++r) {
      const int row = wm2 * 64 + mi * 16 + lg4 * 4 + r;
      if (row < rowLim) {
        const float gt = gts[row];
        float* orow = out + (size_t)toks[row] * D_ + wn2 * 128 + lr;
#pragma unroll
        for (int ni = 0; ni < 8; ++ni)
          atomicAdd(orow + ni * 16, gt * acc[mi][ni][r]);
      }
    }
  }
}

extern "C" void kernel_launch(void* const* d_in, const int* in_sizes, int n_in,
                              void* d_out, int out_size, void* d_ws, size_t ws_size,
                              hipStream_t stream) {
  const float* x  = (const float*)d_in[0];
  const float* Wr = (const float*)d_in[1];
  const float* W1 = (const float*)d_in[2];
  const float* W2 = (const float*)d_in[3];
  float* out = (float*)d_out;

  char* w = (char*)d_ws;
  unsigned short* W1T = (unsigned short*)(w);                    // 16 MiB [E][F][D]
  unsigned short* W2B = (unsigned short*)(w + 16777216);         // 16 MiB frag-ordered
  unsigned short* Xp  = (unsigned short*)(w + 33554432);         // 65 MiB [NSLOT_MAX][D]
  int*   ridx  = (int*)  (w + 101711872);
  float* rwgt  = (float*)(w + 101974016);
  int*   ptok  = (int*)  (w + 102236160);
  float* pgate = (float*)(w + 102502400);
  int*   ctrl  = (int*)  (w + 102768640);

  transpose_cvt_k<<<dim3(F_ / 32, D_ / 32, E_), dim3(32, 8), 0, stream>>>(W1, W1T, D_, F_);
  cvtW2_k<<<4096, 256, 0, stream>>>(W2, W2B);
  router_k<<<N_TOK / 4, 256, 0, stream>>>(x, Wr, ridx, rwgt);
  count_k<<<1, 1024, 0, stream>>>(ridx, ctrl);
  scatter_k<<<N_TOK * 2 / 512, 512, 0, stream>>>(ridx, rwgt, ctrl, ptok, pgate);
  gather_k<<<NSLOT_MAX / 4, 256, 0, stream>>>(x, ptok, ctrl, Xp);
  hipMemsetAsync(out, 0, (size_t)out_size * sizeof(float), stream);
  ffn_k<<<2048, 512, 0, stream>>>(Xp, W1T, W2B, ptok, pgate, ctrl, out);
}

// Round 4
// 862.613 us; speedup vs baseline: 1.9897x; 1.9897x over previous
//
#include <hip/hip_runtime.h>

#define N_TOK 32768
#define D_ 512
#define F_ 2048
#define E_ 8
#define M_TILE 128
#define BF_ 128
#define NSLOT_MAX 66560   // 65536 + 8*128 padding, 128-aligned per expert

typedef __attribute__((ext_vector_type(8))) short bf16x8;
typedef __attribute__((ext_vector_type(8))) unsigned short us8;
typedef __attribute__((ext_vector_type(4))) float f32x4;

__device__ __forceinline__ unsigned short f2bf(float f) {
  union { float f; unsigned u; } v; v.f = f;
  unsigned r = v.u + 0x7fffu + ((v.u >> 16) & 1u);   // RNE; inputs finite
  return (unsigned short)(r >> 16);
}

__device__ __forceinline__ void gload16(const void* g, void* l) {
  __builtin_amdgcn_global_load_lds((const __attribute__((address_space(1))) void*)g,
                                   (__attribute__((address_space(3))) void*)l, 16, 0, 0);
}

// src [E][R][C] f32  ->  dst [E][C][R] bf16 (used for W1 -> [E][F][D])
__global__ void transpose_cvt_k(const float* __restrict__ src,
                                unsigned short* __restrict__ dst, int R, int C) {
  __shared__ unsigned short tl[32][33];
  const int e = blockIdx.z;
  const size_t base = (size_t)e * R * C;
  const int c0 = blockIdx.x * 32, r0 = blockIdx.y * 32;
  const int tx = threadIdx.x, ty = threadIdx.y;
#pragma unroll
  for (int i = 0; i < 4; ++i) {
    int r = ty + i * 8;
    tl[r][tx] = f2bf(src[base + (size_t)(r0 + r) * C + c0 + tx]);
  }
  __syncthreads();
#pragma unroll
  for (int i = 0; i < 4; ++i) {
    int r = ty + i * 8;
    dst[base + (size_t)(c0 + r) * R + r0 + tx] = tl[tx][r];
  }
}

// W2 [E][F][D] f32 -> fragment-ordered bf16:
// dest[((e*64+fb)*32+db)*512 + lane*8 + j] = bf16(W2[e][fb*32+(lane>>4)*8+j][db*16+(lane&15)])
__global__ void cvtW2_k(const float* __restrict__ W2, unsigned short* __restrict__ W2B) {
  const int gid = blockIdx.x * 256 + threadIdx.x;    // 1,048,576 total
  const int l  = gid & 63;
  const int db = (gid >> 6) & 31;
  const int fb = (gid >> 11) & 63;
  const int e  = gid >> 17;
  const int d  = db * 16 + (l & 15);
  const int f0 = fb * 32 + (l >> 4) * 8;
  const float* src = W2 + ((size_t)e * F_ + f0) * D_ + d;
  us8 v;
#pragma unroll
  for (int j = 0; j < 8; ++j) v[j] = f2bf(src[(size_t)j * D_]);
  *reinterpret_cast<us8*>(W2B + (size_t)gid * 8) = v;
}

// one wave per token: logits = x_row @ Wr, softmax fp32, top-2. NO atomics.
__global__ void router_k(const float* __restrict__ x, const float* __restrict__ Wr,
                         int* __restrict__ ridx, float* __restrict__ rw) {
  const int wid = threadIdx.x >> 6, lane = threadIdx.x & 63;
  const int t = blockIdx.x * 4 + wid;
  const float* xr = x + (size_t)t * D_ + lane * 8;
  const float4 xa = *reinterpret_cast<const float4*>(xr);
  const float4 xb = *reinterpret_cast<const float4*>(xr + 4);
  float xv[8] = {xa.x, xa.y, xa.z, xa.w, xb.x, xb.y, xb.z, xb.w};
  float lg[8] = {0, 0, 0, 0, 0, 0, 0, 0};
#pragma unroll
  for (int j = 0; j < 8; ++j) {
    const float* wr = Wr + (size_t)(lane * 8 + j) * E_;
    float4 w0 = *reinterpret_cast<const float4*>(wr);
    float4 w1 = *reinterpret_cast<const float4*>(wr + 4);
    lg[0] += xv[j] * w0.x; lg[1] += xv[j] * w0.y; lg[2] += xv[j] * w0.z; lg[3] += xv[j] * w0.w;
    lg[4] += xv[j] * w1.x; lg[5] += xv[j] * w1.y; lg[6] += xv[j] * w1.z; lg[7] += xv[j] * w1.w;
  }
#pragma unroll
  for (int off = 32; off; off >>= 1) {
#pragma unroll
    for (int q = 0; q < 8; ++q) lg[q] += __shfl_xor(lg[q], off);
  }
  if (lane == 0) {
    float m = lg[0];
#pragma unroll
    for (int q = 1; q < 8; ++q) m = fmaxf(m, lg[q]);
    float p[8]; float s = 0.f;
#pragma unroll
    for (int q = 0; q < 8; ++q) { p[q] = expf(lg[q] - m); s += p[q]; }
    float inv = 1.f / s;
    int e1 = 0;
#pragma unroll
    for (int q = 1; q < 8; ++q) if (p[q] > p[e1]) e1 = q;
    int e2 = (e1 == 0) ? 1 : 0;
#pragma unroll
    for (int q = 0; q < 8; ++q) { if (q == e1) continue; if (p[q] > p[e2]) e2 = q; }
    ridx[2 * t] = e1; ridx[2 * t + 1] = e2;
    rw[2 * t] = p[e1] * inv; rw[2 * t + 1] = p[e2] * inv;
  }
}

// single block: counts, 128-padded offsets, zero cursors
__global__ void count_k(const int* __restrict__ ridx, int* __restrict__ ctrl) {
  __shared__ int h[E_];
  const int tid = threadIdx.x;   // 1024
  if (tid < E_) h[tid] = 0;
  __syncthreads();
  int c0=0,c1=0,c2=0,c3=0,c4=0,c5=0,c6=0,c7=0;
  for (int i = tid; i < 2 * N_TOK; i += 1024) {
    int v = ridx[i];
    c0 += (v == 0); c1 += (v == 1); c2 += (v == 2); c3 += (v == 3);
    c4 += (v == 4); c5 += (v == 5); c6 += (v == 6); c7 += (v == 7);
  }
  atomicAdd(&h[0], c0); atomicAdd(&h[1], c1); atomicAdd(&h[2], c2); atomicAdd(&h[3], c3);
  atomicAdd(&h[4], c4); atomicAdd(&h[5], c5); atomicAdd(&h[6], c6); atomicAdd(&h[7], c7);
  __syncthreads();
  if (tid == 0) {
    int a = 0;
    for (int e = 0; e < E_; ++e) {
      ctrl[e] = h[e];
      ctrl[8 + e] = a;
      a += (h[e] + 127) & ~127;
      ctrl[16 + e] = 0;
    }
    ctrl[24] = a;
  }
}

// per-block LDS ranks + 8 global atomics per block
__global__ void scatter_k(const int* __restrict__ ridx, const float* __restrict__ rw,
                          int* __restrict__ ctrl, int* __restrict__ ptok,
                          float* __restrict__ pgate) {
  __shared__ int h[E_], base[E_];
  const int tid = threadIdx.x;                 // 512
  const int g = blockIdx.x * 512 + tid;        // entry id
  if (tid < E_) h[tid] = 0;
  __syncthreads();
  const int e = ridx[g];
  const int r = atomicAdd(&h[e], 1);           // LDS atomic
  __syncthreads();
  if (tid < E_) base[tid] = atomicAdd(&ctrl[16 + tid], h[tid]);
  __syncthreads();
  const int pos = ctrl[8 + e] + base[e] + r;
  ptok[pos] = g >> 1;
  pgate[pos] = rw[g];
}

// permuted bf16 activations; pad slots zero-filled. one wave per slot.
__global__ void gather_k(const float* __restrict__ x, const int* __restrict__ ptok,
                         const int* __restrict__ ctrl, unsigned short* __restrict__ Xp) {
  const int wid = threadIdx.x >> 6, lane = threadIdx.x & 63;
  const int slot = blockIdx.x * 4 + wid;
  bool valid = false;
#pragma unroll
  for (int e = 0; e < E_; ++e) {
    int off = ctrl[8 + e], c = ctrl[e];
    valid = valid || (slot >= off && slot < off + c);
  }
  us8 v;
  if (valid) {
    const int tok = ptok[slot];
    const float* src = x + (size_t)tok * D_ + lane * 8;
    float4 a = *reinterpret_cast<const float4*>(src);
    float4 b = *reinterpret_cast<const float4*>(src + 4);
    v[0] = f2bf(a.x); v[1] = f2bf(a.y); v[2] = f2bf(a.z); v[3] = f2bf(a.w);
    v[4] = f2bf(b.x); v[5] = f2bf(b.y); v[6] = f2bf(b.z); v[7] = f2bf(b.w);
  } else {
    v = (us8){0, 0, 0, 0, 0, 0, 0, 0};
  }
  *reinterpret_cast<us8*>(Xp + (size_t)slot * D_ + lane * 8) = v;
}

// R2 structure + T2 both-sides XOR swizzle on GEMM1 tiles + expert<->XCD affinity.
// LDS tiles [128 rows][64 k] linear rows of 128B; 16B-chunk c of row r holds global
// chunk c^(r&7) (pre-swizzled global_load_lds source); ds_read applies same XOR.
__global__ __launch_bounds__(512, 2) void ffn_k(
    const unsigned short* __restrict__ Xp,
    const unsigned short* __restrict__ W1T,   // [E][F][D] bf16 row-major
    const unsigned short* __restrict__ W2B,   // fragment-ordered
    const int* __restrict__ ptok, const float* __restrict__ pgate,
    const int* __restrict__ ctrl, float* __restrict__ out) {
  const int gid = blockIdx.x;
  const int e = gid & 7;                      // XCD affinity
  const int cnt = ctrl[e];
  const int tile0 = (gid >> 3) * M_TILE;
  if (tile0 >= cnt) return;
  const int slot0 = ctrl[8 + e] + tile0;

  __shared__ unsigned short Xs[2][8192];     // [128 rows][64 k], swizzled chunks
  __shared__ unsigned short W1s[2][8192];
  __shared__ unsigned short Hs[M_TILE][BF_ + 8];
  __shared__ int   toks[M_TILE];
  __shared__ float gts[M_TILE];

  const int tid = threadIdx.x;
  if (tid < M_TILE) {
    int slot = tile0 + tid;
    toks[tid] = (slot < cnt) ? ptok[slot0 + tid] : 0;
    gts[tid]  = (slot < cnt) ? pgate[slot0 + tid] : 0.f;
  }

  const int wid = tid >> 6, lane = tid & 63;
  const int lr = lane & 15, lg4 = lane >> 4;
  const int lx = lr & 7;                     // row XOR key for fragment reads
  const int wm1 = wid >> 1, wn1 = wid & 1;   // GEMM1: 4x2 waves over 128x128
  const int wm2 = wid >> 2, wn2 = wid & 3;   // GEMM2: 2x4 waves over 128x512

  const char* XB  = (const char*)(Xp + (size_t)slot0 * D_);     // row stride 1024B
  const char* W1B = (const char*)(W1T + (size_t)e * (F_ * D_));
  const unsigned short* W2e = W2B + (size_t)e * (F_ * D_);

  // staging: thread covers linear dest offsets o0 (rows 0..63) and o1 (rows 64..127)
  const int o0 = tid * 16, o1 = (512 + tid) * 16;
  const int r0 = o0 >> 7, r1 = o1 >> 7;     // r1 = r0 + 64, same (r&7)
  const int cs = (((tid & 7) ^ (r0 & 7)) << 4);  // swizzled source chunk byte offset

  f32x4 acc[4][8];
#pragma unroll
  for (int i = 0; i < 4; ++i)
#pragma unroll
    for (int j = 0; j < 8; ++j) acc[i][j] = {0.f, 0.f, 0.f, 0.f};

  // prologue: stage (jF=0, kb=0) into buf0
  gload16(XB + (size_t)r0 * 1024 + cs, (char*)Xs[0] + o0);
  gload16(XB + (size_t)r1 * 1024 + cs, (char*)Xs[0] + o1);
  gload16(W1B + (size_t)r0 * 1024 + cs, (char*)W1s[0] + o0);
  gload16(W1B + (size_t)r1 * 1024 + cs, (char*)W1s[0] + o1);
  __syncthreads();   // drain + barrier (also covers toks/gts)

  for (int jF = 0; jF < F_; jF += BF_) {
    f32x4 hacc[2][4];
#pragma unroll
    for (int i = 0; i < 2; ++i)
#pragma unroll
      for (int j = 0; j < 4; ++j) hacc[i][j] = {0.f, 0.f, 0.f, 0.f};

    for (int kb = 0; kb < 8; ++kb) {
      const int cur = kb & 1;
      const bool last = (kb == 7) && (jF == F_ - BF_);
      if (!last) {
        const int nkb = (kb < 7) ? kb + 1 : 0;
        const int njf = (kb < 7) ? jF : jF + BF_;
        const size_t xo = (size_t)nkb * 128;
        gload16(XB + (size_t)r0 * 1024 + xo + cs, (char*)Xs[cur ^ 1] + o0);
        gload16(XB + (size_t)r1 * 1024 + xo + cs, (char*)Xs[cur ^ 1] + o1);
        const char* wb = W1B + (size_t)njf * 1024 + nkb * 128;
        gload16(wb + (size_t)r0 * 1024 + cs, (char*)W1s[cur ^ 1] + o0);
        gload16(wb + (size_t)r1 * 1024 + cs, (char*)W1s[cur ^ 1] + o1);
      }
      // compute on buf cur; fragment chunk g = ks*4+lg4, lds chunk = g ^ (row&7)
#pragma unroll
      for (int ks = 0; ks < 2; ++ks) {
        const int ch = (((ks << 2) | lg4) ^ lx) << 3;   // ushort offset within row
        bf16x8 af[2], bw[4];
#pragma unroll
        for (int mi = 0; mi < 2; ++mi)
          af[mi] = *reinterpret_cast<const bf16x8*>(&Xs[cur][(wm1 * 32 + mi * 16 + lr) * 64 + ch]);
#pragma unroll
        for (int ni = 0; ni < 4; ++ni)
          bw[ni] = *reinterpret_cast<const bf16x8*>(&W1s[cur][(wn1 * 64 + ni * 16 + lr) * 64 + ch]);
#pragma unroll
        for (int mi = 0; mi < 2; ++mi)
#pragma unroll
          for (int ni = 0; ni < 4; ++ni)
            hacc[mi][ni] = __builtin_amdgcn_mfma_f32_16x16x32_bf16(af[mi], bw[ni], hacc[mi][ni], 0, 0, 0);
      }
      asm volatile("s_waitcnt vmcnt(0)" ::: "memory");
      __builtin_amdgcn_s_barrier();
    }

    // exact GELU -> Hs (bf16)
#pragma unroll
    for (int mi = 0; mi < 2; ++mi)
#pragma unroll
      for (int ni = 0; ni < 4; ++ni)
#pragma unroll
        for (int r = 0; r < 4; ++r) {
          float v = hacc[mi][ni][r];
          float g = 0.5f * v * (1.f + erff(v * 0.70710678118654752f));
          Hs[wm1 * 32 + mi * 16 + lg4 * 4 + r][wn1 * 64 + ni * 16 + lr] = f2bf(g);
        }
    __syncthreads();

    // GEMM2: A from Hs (padded LDS), B from W2B (global, coalesced, L2-hot)
#pragma unroll
    for (int kb2 = 0; kb2 < 4; ++kb2) {
      const int fb = (jF >> 5) + kb2;
      bf16x8 bw2[8], ah[4];
#pragma unroll
      for (int ni = 0; ni < 8; ++ni)
        bw2[ni] = *reinterpret_cast<const bf16x8*>(W2e + ((size_t)fb * 32 + wn2 * 8 + ni) * 512 + lane * 8);
#pragma unroll
      for (int mi = 0; mi < 4; ++mi)
        ah[mi] = *reinterpret_cast<const bf16x8*>(&Hs[wm2 * 64 + mi * 16 + lr][kb2 * 32 + lg4 * 8]);
#pragma unroll
      for (int mi = 0; mi < 4; ++mi)
#pragma unroll
        for (int ni = 0; ni < 8; ++ni)
          acc[mi][ni] = __builtin_amdgcn_mfma_f32_16x16x32_bf16(ah[mi], bw2[ni], acc[mi][ni], 0, 0, 0);
    }
    __syncthreads();
  }

  // epilogue: scale by gate, atomic-add (exactly 2 adds/elem -> deterministic)
  const int rowLim = cnt - tile0;
#pragma unroll
  for (int mi = 0; mi < 4; ++mi) {
#pragma unroll
    for (int r = 0; r < 4; ++r) {
      const int row = wm2 * 64 + mi * 16 + lg4 * 4 + r;
      if (row < rowLim) {
        const float gt = gts[row];
        float* orow = out + (size_t)toks[row] * D_ + wn2 * 128 + lr;
#pragma unroll
        for (int ni = 0; ni < 8; ++ni)
          atomicAdd(orow + ni * 16, gt * acc[mi][ni][r]);
      }
    }
  }
}

extern "C" void kernel_launch(void* const* d_in, const int* in_sizes, int n_in,
                              void* d_out, int out_size, void* d_ws, size_t ws_size,
                              hipStream_t stream) {
  const float* x  = (const float*)d_in[0];
  const float* Wr = (const float*)d_in[1];
  const float* W1 = (const float*)d_in[2];
  const float* W2 = (const float*)d_in[3];
  float* out = (float*)d_out;

  char* w = (char*)d_ws;
  unsigned short* W1T = (unsigned short*)(w);                    // 16 MiB [E][F][D]
  unsigned short* W2B = (unsigned short*)(w + 16777216);         // 16 MiB frag-ordered
  unsigned short* Xp  = (unsigned short*)(w + 33554432);         // 65 MiB [NSLOT_MAX][D]
  int*   ridx  = (int*)  (w + 101711872);
  float* rwgt  = (float*)(w + 101974016);
  int*   ptok  = (int*)  (w + 102236160);
  float* pgate = (float*)(w + 102502400);
  int*   ctrl  = (int*)  (w + 102768640);

  transpose_cvt_k<<<dim3(F_ / 32, D_ / 32, E_), dim3(32, 8), 0, stream>>>(W1, W1T, D_, F_);
  cvtW2_k<<<4096, 256, 0, stream>>>(W2, W2B);
  router_k<<<N_TOK / 4, 256, 0, stream>>>(x, Wr, ridx, rwgt);
  count_k<<<1, 1024, 0, stream>>>(ridx, ctrl);
  scatter_k<<<N_TOK * 2 / 512, 512, 0, stream>>>(ridx, rwgt, ctrl, ptok, pgate);
  gather_k<<<NSLOT_MAX / 4, 256, 0, stream>>>(x, ptok, ctrl, Xp);
  hipMemsetAsync(out, 0, (size_t)out_size * sizeof(float), stream);
  ffn_k<<<2048, 512, 0, stream>>>(Xp, W1T, W2B, ptok, pgate, ctrl, out);
}